// Round 2
// baseline (1197.647 us; speedup 1.0000x reference)
//
#include <hip/hip_runtime.h>
#include <math.h>

#define T_TOK 8192
#define DDIM  4096
#define NEXP  64
#define TOPK  8

#define TSTRIP   32      // tokens per block strip
#define PANELK   64      // k per panel (= W regs per lane)
#define TPW      8       // tokens per wave

// ---- Kernel 0: transpose gate_weight [E][D] -> WT [D][E] ----
__global__ __launch_bounds__(256) void transpose_w(
    const float* __restrict__ gw, float* __restrict__ wt)
{
    int idx = blockIdx.x * 256 + threadIdx.x;   // over D*E
    int e = idx & (NEXP - 1);
    int k = idx >> 6;
    wt[idx] = gw[(size_t)e * DDIM + k];
}

// ---- Kernel 1: logits partials ----
// 256 thr = 4 waves; strip of 32 tokens; slice s covers kprime ks.
// lane = expert. Per 64-k panel: all waves load identical W[lane][kp..]
// into regs (coalesced via WT); x panel staged in LDS; each wave computes
// its own 8 tokens via uniform-address (broadcast) float4 LDS reads.
__global__ __launch_bounds__(256, 4) void gemm_logits(
    const float* __restrict__ x, const float* __restrict__ wt,
    float* __restrict__ part, int S, int kprime)
{
    __shared__ float xs[TSTRIP * PANELK];   // 8 KB

    const int nstrip = T_TOK / TSTRIP;      // 256
    const int strip  = blockIdx.x % nstrip;
    const int s      = blockIdx.x / nstrip;
    const int tok0   = strip * TSTRIP;
    const int kbeg   = s * kprime;

    const int tid  = threadIdx.x;
    const int lane = tid & 63;
    const int wave = tid >> 6;
    const int t0   = wave * TPW;

    float acc[TPW];
    #pragma unroll
    for (int i = 0; i < TPW; i++) acc[i] = 0.f;

    float w[PANELK];

    const int npanel = kprime / PANELK;
    for (int p = 0; p < npanel; p++) {
        const int kp = kbeg + p * PANELK;

        // stage x[tok0..tok0+31][kp..kp+63] -> xs (coalesced float4, no conflicts)
        #pragma unroll
        for (int r = 0; r < 2; r++) {
            int f = r * 256 + tid;          // float4 id, 512 total
            int t = f >> 4;                 // 16 float4 per row
            int c = f & 15;
            float4 v = *reinterpret_cast<const float4*>(
                x + (size_t)(tok0 + t) * DDIM + kp + c * 4);
            *reinterpret_cast<float4*>(&xs[t * PANELK + c * 4]) = v;
        }

        // W register fill (coalesced: lane = expert, consecutive in WT row)
        const float* wtp = wt + (size_t)kp * NEXP + lane;
        #pragma unroll
        for (int j = 0; j < PANELK; j++) w[j] = wtp[(size_t)j * NEXP];

        __syncthreads();

        #pragma unroll
        for (int tt = 0; tt < TPW; tt++) {
            const float4* xr = reinterpret_cast<const float4*>(
                &xs[(t0 + tt) * PANELK]);
            float a0 = 0.f, a1 = 0.f, a2 = 0.f, a3 = 0.f;
            #pragma unroll
            for (int j4 = 0; j4 < PANELK / 4; j4++) {
                float4 xv = xr[j4];         // uniform addr -> broadcast, 0 conflicts
                a0 = fmaf(xv.x, w[4 * j4 + 0], a0);
                a1 = fmaf(xv.y, w[4 * j4 + 1], a1);
                a2 = fmaf(xv.z, w[4 * j4 + 2], a2);
                a3 = fmaf(xv.w, w[4 * j4 + 3], a3);
            }
            acc[tt] += (a0 + a1) + (a2 + a3);
        }
        __syncthreads();
    }

    float* pout = part + (size_t)s * T_TOK * NEXP
                + (size_t)(tok0 + t0) * NEXP + lane;
    #pragma unroll
    for (int tt = 0; tt < TPW; tt++)
        pout[(size_t)tt * NEXP] = acc[tt];
}

// ---- Kernel 2: reduce partials, sigmoid, +bias, top-8, normalize ----
__global__ __launch_bounds__(256) void reduce_topk(
    const float* __restrict__ part, const float* __restrict__ bias,
    float* __restrict__ out, int S)
{
    const int wave  = threadIdx.x >> 6;
    const int lane  = threadIdx.x & 63;
    const int token = blockIdx.x * 4 + wave;
    if (token >= T_TOK) return;

    float logit = 0.f;
    for (int s = 0; s < S; s++)
        logit += part[(size_t)s * T_TOK * NEXP + (size_t)token * NEXP + lane];

    float score  = 1.f / (1.f + expf(-logit));
    float biased = score + bias[lane];

    float my_sc = 0.f;
    int   my_idx = 0;
    float ssum  = 0.f;

    #pragma unroll
    for (int j = 0; j < TOPK; j++) {
        float v = biased;
        int   i = lane;
        #pragma unroll
        for (int off = 32; off >= 1; off >>= 1) {
            float ov = __shfl_xor(v, off);
            int   oi = __shfl_xor(i, off);
            if (ov > v || (ov == v && oi < i)) { v = ov; i = oi; }
        }
        float s_sel = __shfl(score, i);
        ssum += s_sel;
        if (lane == j) { my_idx = i; my_sc = s_sel; }
        if (lane == i) biased = -INFINITY;
    }

    if (lane < TOPK) {
        out[(size_t)token * TOPK + lane] = (float)my_idx;                 // indices as f32
        out[(size_t)T_TOK * TOPK + (size_t)token * TOPK + lane]
            = my_sc / (ssum + 1e-20f);                                    // weights
    }
}

extern "C" void kernel_launch(void* const* d_in, const int* in_sizes, int n_in,
                              void* d_out, int out_size, void* d_ws, size_t ws_size,
                              hipStream_t stream) {
    (void)in_sizes; (void)n_in; (void)out_size;
    const float* x    = (const float*)d_in[0];
    const float* gw   = (const float*)d_in[1];
    const float* bias = (const float*)d_in[2];
    float* out  = (float*)d_out;
    float* wt   = (float*)d_ws;                      // [DDIM][NEXP], 1 MiB
    float* part = wt + (size_t)DDIM * NEXP;          // S x [T][E]

    const size_t wt_bytes  = (size_t)DDIM * NEXP * sizeof(float);
    const size_t per_slice = (size_t)T_TOK * NEXP * sizeof(float);   // 2 MiB
    int S = 1;
    for (int cand : {8, 4, 2}) {
        if (wt_bytes + (size_t)cand * per_slice <= ws_size) { S = cand; break; }
    }
    int kprime = DDIM / S;

    transpose_w<<<DDIM * NEXP / 256, 256, 0, stream>>>(gw, wt);

    dim3 g1((T_TOK / TSTRIP) * S), b1(256);
    gemm_logits<<<g1, b1, 0, stream>>>(x, wt, part, S, kprime);

    dim3 g2((T_TOK + 3) / 4), b2(256);
    reduce_topk<<<g2, b2, 0, stream>>>(part, bias, out, S);
}

// Round 3
// 82.046 us; speedup vs baseline: 14.5973x; 14.5973x over previous
//
#include <hip/hip_runtime.h>
#include <math.h>

#define T_TOK 8192
#define DDIM  4096
#define NEXP  64
#define TOPK  8

#define MTILE 128
#define BK    64
#define NTH   256

// ---- K0: transpose gate_weight [E][D] -> wt [D][E] (coalesced reads) ----
__global__ __launch_bounds__(256) void transpose_w(
    const float* __restrict__ gw, float* __restrict__ wt)
{
    int idx = blockIdx.x * 256 + threadIdx.x;   // idx = e*DDIM + k
    int e = idx >> 12;
    int k = idx & (DDIM - 1);
    wt[(size_t)k * NEXP + e] = gw[idx];
}

// ---- K1: logits partials. C-tile 128 tok x 64 exp, frag 4x8/thread. ----
// A staged [m][k] float4 with XOR-swizzled k-group (conflict-free store+load).
// B staged linear [k][e] from pre-transposed wt (conflict-free memcpy).
__global__ __launch_bounds__(NTH) void gemm_logits(
    const float* __restrict__ x, const float* __restrict__ wt,
    float* __restrict__ part, int S, int kprime)
{
    __shared__ float A[MTILE * BK];   // 32 KB, swizzled
    __shared__ float B[BK * NEXP];    // 16 KB, linear

    const int nmt = T_TOK / MTILE;    // 64
    const int mt  = blockIdx.x % nmt;
    const int s   = blockIdx.x / nmt;
    const int m0  = mt * MTILE;
    const int kb  = s * kprime;

    const int t    = threadIdx.x;
    const int lane = t & 63;
    const int w    = t >> 6;
    const int tn   = lane & 7;        // expert group
    const int tm   = lane >> 3;       // 0..7
    const int rowb = w * 32 + tm * 4; // frag token base within tile
    const int mg   = (rowb >> 2) & 15;

    float acc[4][8];
    #pragma unroll
    for (int i = 0; i < 4; i++)
        #pragma unroll
        for (int j = 0; j < 8; j++) acc[i][j] = 0.f;

    for (int p = 0; p < kprime; p += BK) {
        // stage A: 128x64 floats = 2048 f4, 8 per thread, coalesced
        #pragma unroll
        for (int r = 0; r < 8; r++) {
            int idx = r * NTH + t;
            int mr  = idx >> 4;           // token 0..127
            int c   = idx & 15;           // k-group 0..15
            float4 v = *reinterpret_cast<const float4*>(
                x + (size_t)(m0 + mr) * DDIM + kb + p + c * 4);
            int g = c ^ ((mr >> 2) & 15);
            *reinterpret_cast<float4*>(&A[mr * BK + g * 4]) = v;
        }
        // stage B: 64x64 floats = 1024 f4, 4 per thread, linear copy
        const float* wsrc = wt + (size_t)(kb + p) * NEXP;
        #pragma unroll
        for (int r = 0; r < 4; r++) {
            int idx = r * NTH + t;
            *reinterpret_cast<float4*>(&B[idx * 4]) =
                *reinterpret_cast<const float4*>(wsrc + idx * 4);
        }
        __syncthreads();

        #pragma unroll
        for (int k4 = 0; k4 < BK / 4; k4++) {
            float4 a[4];
            const int g = (k4 ^ mg) & 15;
            #pragma unroll
            for (int i = 0; i < 4; i++)
                a[i] = *reinterpret_cast<const float4*>(&A[(rowb + i) * BK + g * 4]);
            const float* af = reinterpret_cast<const float*>(a);
            #pragma unroll
            for (int kk = 0; kk < 4; kk++) {
                float4 b0 = *reinterpret_cast<const float4*>(&B[(k4 * 4 + kk) * NEXP + tn * 8]);
                float4 b1 = *reinterpret_cast<const float4*>(&B[(k4 * 4 + kk) * NEXP + tn * 8 + 4]);
                const float bv[8] = {b0.x, b0.y, b0.z, b0.w, b1.x, b1.y, b1.z, b1.w};
                #pragma unroll
                for (int i = 0; i < 4; i++) {
                    float av = af[i * 4 + kk];
                    #pragma unroll
                    for (int j = 0; j < 8; j++)
                        acc[i][j] = fmaf(av, bv[j], acc[i][j]);
                }
            }
        }
        __syncthreads();
    }

    // write partials: part[s][token][expert]
    float* pout = part + (size_t)s * T_TOK * NEXP + (size_t)m0 * NEXP;
    #pragma unroll
    for (int i = 0; i < 4; i++) {
        int row = rowb + i;
        float4 w0 = make_float4(acc[i][0], acc[i][1], acc[i][2], acc[i][3]);
        float4 w1 = make_float4(acc[i][4], acc[i][5], acc[i][6], acc[i][7]);
        *reinterpret_cast<float4*>(&pout[(size_t)row * NEXP + tn * 8])     = w0;
        *reinterpret_cast<float4*>(&pout[(size_t)row * NEXP + tn * 8 + 4]) = w1;
    }
}

// ---- K2: reduce partials, sigmoid, +bias, top-8, normalize ----
__global__ __launch_bounds__(256) void reduce_topk(
    const float* __restrict__ part, const float* __restrict__ bias,
    float* __restrict__ out, int S)
{
    const int wave  = threadIdx.x >> 6;
    const int lane  = threadIdx.x & 63;
    const int token = blockIdx.x * 4 + wave;
    if (token >= T_TOK) return;

    float logit = 0.f;
    for (int s = 0; s < S; s++)
        logit += part[(size_t)s * T_TOK * NEXP + (size_t)token * NEXP + lane];

    float score  = 1.f / (1.f + expf(-logit));
    float biased = score + bias[lane];

    float my_sc = 0.f;
    int   my_idx = 0;
    float ssum  = 0.f;

    #pragma unroll
    for (int j = 0; j < TOPK; j++) {
        float v = biased;
        int   i = lane;
        #pragma unroll
        for (int off = 32; off >= 1; off >>= 1) {
            float ov = __shfl_xor(v, off);
            int   oi = __shfl_xor(i, off);
            if (ov > v || (ov == v && oi < i)) { v = ov; i = oi; }
        }
        float s_sel = __shfl(score, i);
        ssum += s_sel;
        if (lane == j) { my_idx = i; my_sc = s_sel; }
        if (lane == i) biased = -INFINITY;
    }

    if (lane < TOPK) {
        out[(size_t)token * TOPK + lane] = (float)my_idx;                 // indices as f32
        out[(size_t)T_TOK * TOPK + (size_t)token * TOPK + lane]
            = my_sc / (ssum + 1e-20f);                                    // weights
    }
}

extern "C" void kernel_launch(void* const* d_in, const int* in_sizes, int n_in,
                              void* d_out, int out_size, void* d_ws, size_t ws_size,
                              hipStream_t stream) {
    (void)in_sizes; (void)n_in; (void)out_size;
    const float* x    = (const float*)d_in[0];
    const float* gw   = (const float*)d_in[1];
    const float* bias = (const float*)d_in[2];
    float* out  = (float*)d_out;
    float* wt   = (float*)d_ws;                     // [DDIM][NEXP], 1 MiB
    float* part = wt + (size_t)DDIM * NEXP;

    const size_t wt_bytes  = (size_t)DDIM * NEXP * sizeof(float);
    const size_t per_slice = (size_t)T_TOK * NEXP * sizeof(float);  // 2 MiB
    int S = 1;
    for (int cand : {8, 4, 2}) {
        if (wt_bytes + (size_t)cand * per_slice <= ws_size) { S = cand; break; }
    }
    int kprime = DDIM / S;

    transpose_w<<<DDIM * NEXP / 256, 256, 0, stream>>>(gw, wt);

    dim3 g1((T_TOK / MTILE) * S), b1(NTH);
    gemm_logits<<<g1, b1, 0, stream>>>(x, wt, part, S, kprime);

    dim3 g2((T_TOK + 3) / 4), b2(256);
    reduce_topk<<<g2, b2, 0, stream>>>(part, bias, out, S);
}